// Round 1
// baseline (69.070 us; speedup 1.0000x reference)
//
#include <hip/hip_runtime.h>
#include <math.h>

// Hawkes point process log-likelihood, B=8, N=4096.
// lamb[b,i] = softplus(alpha)*softplus(beta)*S_i + softplus(mu),
//   S_i = sum_{j<i} exp(-beta*(t_i - t_j))   (O(N) affine scan, not O(N^2))
// out[b] = sum_i log(lamb+1e-8)*m_i - [(t1-t0)*mu - alpha*(sum_i exp(lk_i) - sum_i m_i)]
//   lk_i = -beta*(t1 - t_i)*m_i + (1-m_i)*(-1e20)

#define NB 256            // threads per block
#define NN 4096           // N (fixed by problem)
#define CC (NN / NB)      // 16 events per thread
#define NW (NB / 64)      // waves per block

__global__ __launch_bounds__(NB) void hawkes_kernel(
    const float* __restrict__ T, const float* __restrict__ M,
    const float* __restrict__ t0, const float* __restrict__ t1,
    const float* __restrict__ mu, const float* __restrict__ alpha,
    const float* __restrict__ beta, float* __restrict__ out, int N)
{
    const int b    = blockIdx.x;
    const int tid  = threadIdx.x;
    const int lane = tid & 63;
    const int wv   = tid >> 6;

    __shared__ float sh_t[NN];
    __shared__ float wd[NW], ww[NW];
    __shared__ float red[3][NW];

    const float* Tb = T + (size_t)b * N;
    const float* Mb = M + (size_t)b * N;

    // coalesced stage of event times into LDS (16 KB)
    for (int i = tid; i < N; i += NB) sh_t[i] = Tb[i];
    __syncthreads();

    // softplus'd params (scalar, every thread computes — cheap)
    const float mu_s = log1pf(expf(mu[0]));
    const float al_s = log1pf(expf(alpha[0]));
    const float be_s = log1pf(expf(beta[0]));
    const float ab   = al_s * be_s;
    const float t1v  = t1[b];
    const float t0v  = t0[b];

    const int s = tid * CC;     // this thread's chunk start

    // ---- pass 1: per-thread sequential within-chunk recurrence ----
    // within[k] = sum_{s<=j<s+k} exp(-beta*(t_{s+k}-t_j)); decay[k] = exp(-beta*(t_{s+k}-t_s))
    float within[CC], decay[CC];
    float w = 0.f, d = 1.f;
    float tprev = sh_t[s];
    within[0] = 0.f; decay[0] = 1.f;
    for (int k = 1; k < CC; ++k) {
        float ti = sh_t[s + k];
        float a  = expf(-be_s * (ti - tprev));
        w = a * (w + 1.f);
        d = d * a;
        within[k] = w; decay[k] = d;
        tprev = ti;
    }
    // affine element mapping carry-entering-this-chunk -> carry-entering-next-chunk:
    // c_next = D*c + W, evaluated at next chunk's first event time
    float D, W;
    if (s + CC < N) {
        float tn = sh_t[s + CC];
        float a  = expf(-be_s * (tn - tprev));
        W = a * (w + 1.f);
        D = d * a;
    } else { D = 0.f; W = 0.f; }  // last chunk of row: unused

    // ---- intra-wave inclusive affine scan (Hillis-Steele, compose (d,w)) ----
    float di = D, wi = W;
    for (int off = 1; off < 64; off <<= 1) {
        float dp = __shfl_up(di, off);
        float wp = __shfl_up(wi, off);
        if (lane >= off) { wi = di * wp + wi; di = di * dp; }  // order matters: wi uses old di
    }
    if (lane == 63) { wd[wv] = di; ww[wv] = wi; }
    __syncthreads();

    // carry entering this wave: apply earlier waves' aggregates in order
    float cw = 0.f;
    for (int j = 0; j < wv; ++j) cw = wd[j] * cw + ww[j];

    // lane-exclusive scan = previous lane's inclusive; identity for lane 0
    float de = __shfl_up(di, 1);
    float we = __shfl_up(wi, 1);
    if (lane == 0) { de = 1.f; we = 0.f; }
    const float carry = de * cw + we;   // S at this thread's chunk start

    // ---- pass 2: lambda, loglik, compensator pieces ----
    float ll = 0.f, ce = 0.f, ms = 0.f;
    for (int k = 0; k < CC; ++k) {
        int i = s + k;
        float ti = sh_t[i];
        float m  = Mb[i];
        float S  = decay[k] * carry + within[k];
        float lamb = ab * S + mu_s;
        ll += logf(lamb + 1e-8f) * m;
        float lk = -be_s * (t1v - ti) * m + (1.f - m) * (-1e20f);
        ce += expf(lk);                 // expf(-1e20) -> 0 for masked
        ms += m;
    }

    // ---- block reduction of (ll, ce, ms) ----
    for (int off = 32; off > 0; off >>= 1) {
        ll += __shfl_down(ll, off);
        ce += __shfl_down(ce, off);
        ms += __shfl_down(ms, off);
    }
    if (lane == 0) { red[0][wv] = ll; red[1][wv] = ce; red[2][wv] = ms; }
    __syncthreads();
    if (tid == 0) {
        float L = 0.f, C = 0.f, Msum = 0.f;
        for (int j = 0; j < NW; ++j) { L += red[0][j]; C += red[1][j]; Msum += red[2][j]; }
        float comp = (t1v - t0v) * mu_s - al_s * (C - Msum);
        out[b] = L - comp;
    }
}

extern "C" void kernel_launch(void* const* d_in, const int* in_sizes, int n_in,
                              void* d_out, int out_size, void* d_ws, size_t ws_size,
                              hipStream_t stream) {
    (void)n_in; (void)d_ws; (void)ws_size;
    const float* T     = (const float*)d_in[0];
    const float* M     = (const float*)d_in[1];
    const float* t0    = (const float*)d_in[2];
    const float* t1    = (const float*)d_in[3];
    const float* mu    = (const float*)d_in[4];
    const float* alpha = (const float*)d_in[5];
    const float* beta  = (const float*)d_in[6];
    float* out = (float*)d_out;

    const int B = in_sizes[2];            // t0 has B elements
    const int N = in_sizes[0] / B;        // 4096

    hawkes_kernel<<<B, NB, 0, stream>>>(T, M, t0, t1, mu, alpha, beta, out, N);
    (void)out_size;
}

// Round 2
// 66.372 us; speedup vs baseline: 1.0407x; 1.0407x over previous
//
#include <hip/hip_runtime.h>
#include <math.h>

// Hawkes point process log-likelihood, B=8, N=4096.
// S_i = sum_{j<i} exp(-beta*(t_i - t_j)) via O(N) affine scan:
//   S_i = a_i*(S_{i-1}+1), a_i = exp(-beta*(t_i - t_{i-1}))
// lamb[b,i] = softplus(alpha)*softplus(beta)*S_i + softplus(mu)
// out[b] = sum_i log(lamb+1e-8)*m_i - [(t1-t0)*mu - alpha*(sum_i exp(lk_i) - sum_i m_i)]
//
// Latency-bound micro-kernel (8 blocks): no LDS staging (direct float4 chunk
// loads), transcendentals hoisted out of the recurrence so dependent chains
// are pure fma.

#define NB 256            // threads per block
#define CC 16             // events per thread (N=4096)
#define NW (NB / 64)      // waves per block

__global__ __launch_bounds__(NB) void hawkes_kernel(
    const float* __restrict__ T, const float* __restrict__ M,
    const float* __restrict__ t0, const float* __restrict__ t1,
    const float* __restrict__ mu, const float* __restrict__ alpha,
    const float* __restrict__ beta, float* __restrict__ out, int N)
{
    const int b    = blockIdx.x;
    const int tid  = threadIdx.x;
    const int lane = tid & 63;
    const int wv   = tid >> 6;

    __shared__ float wd[NW], ww[NW];
    __shared__ float red[3][NW];

    const float* Tb = T + (size_t)b * N;
    const float* Mb = M + (size_t)b * N;
    const int s = tid * CC;

    // ---- direct vector loads of this thread's contiguous chunk ----
    float t[CC], m[CC];
    const float4* T4 = (const float4*)(Tb + s);
    const float4* M4 = (const float4*)(Mb + s);
#pragma unroll
    for (int q = 0; q < CC / 4; ++q) {
        float4 tv = T4[q], mv = M4[q];
        t[4*q+0] = tv.x; t[4*q+1] = tv.y; t[4*q+2] = tv.z; t[4*q+3] = tv.w;
        m[4*q+0] = mv.x; m[4*q+1] = mv.y; m[4*q+2] = mv.z; m[4*q+3] = mv.w;
    }
    const bool has_next = (s + CC < N);
    const float tn = has_next ? Tb[s + CC] : 0.f;   // next chunk's first event

    // softplus'd params (scalar broadcast loads, cheap)
    const float mu_s = log1pf(expf(mu[0]));
    const float al_s = log1pf(expf(alpha[0]));
    const float be_s = log1pf(expf(beta[0]));
    const float ab   = al_s * be_s;
    const float t1v  = t1[b];
    const float t0v  = t0[b];

    // ---- independent transcendentals (pipelined), then fma-only recurrence ----
    float a[CC];
#pragma unroll
    for (int k = 1; k < CC; ++k) a[k] = __expf(-be_s * (t[k] - t[k-1]));
    const float aN = __expf(-be_s * (tn - t[CC-1]));  // garbage if !has_next (unused)

    // within[k] = sum_{s<=j<s+k} exp(-beta*(t_{s+k}-t_j)); decay[k] = exp(-beta*(t_{s+k}-t_s))
    float within[CC], decay[CC];
    within[0] = 0.f; decay[0] = 1.f;
    float w = 0.f, d = 1.f;
#pragma unroll
    for (int k = 1; k < CC; ++k) {
        w = a[k] * (w + 1.f);
        d = d * a[k];
        within[k] = w; decay[k] = d;
    }
    // chunk aggregate: carry-entering-next = D*carry + W (evaluated at next chunk's t)
    float D = has_next ? d * aN        : 0.f;
    float W = has_next ? aN * (w + 1.f): 0.f;

    // ---- intra-wave inclusive affine scan (Hillis-Steele over (d,w)) ----
    float di = D, wi = W;
#pragma unroll
    for (int off = 1; off < 64; off <<= 1) {
        float dp = __shfl_up(di, off);
        float wp = __shfl_up(wi, off);
        if (lane >= off) { wi = di * wp + wi; di = di * dp; }
    }
    if (lane == 63) { wd[wv] = di; ww[wv] = wi; }
    __syncthreads();

    // carry entering this wave
    float cw = 0.f;
    for (int j = 0; j < wv; ++j) cw = wd[j] * cw + ww[j];

    // lane-exclusive = previous lane's inclusive
    float de = __shfl_up(di, 1);
    float we = __shfl_up(wi, 1);
    if (lane == 0) { de = 1.f; we = 0.f; }
    const float carry = de * cw + we;   // S at this thread's chunk start

    // ---- pass 2: loglik + compensator pieces (split accumulators) ----
    float ll0 = 0.f, ll1 = 0.f, ce0 = 0.f, ce1 = 0.f, ms = 0.f;
#pragma unroll
    for (int k = 0; k < CC; ++k) {
        float S    = fmaf(decay[k], carry, within[k]);
        float lamb = fmaf(ab, S, mu_s);
        float lg   = __logf(lamb + 1e-8f) * m[k];
        float lk   = fmaf(-be_s * (t1v - t[k]), m[k], (1.f - m[k]) * (-1e20f));
        float ev   = __expf(lk);        // -> 0 for masked entries
        if (k & 1) { ll1 += lg; ce1 += ev; } else { ll0 += lg; ce0 += ev; }
        ms += m[k];
    }
    float ll = ll0 + ll1, ce = ce0 + ce1;

    // ---- block reduction of (ll, ce, ms) ----
#pragma unroll
    for (int off = 32; off > 0; off >>= 1) {
        ll += __shfl_down(ll, off);
        ce += __shfl_down(ce, off);
        ms += __shfl_down(ms, off);
    }
    if (lane == 0) { red[0][wv] = ll; red[1][wv] = ce; red[2][wv] = ms; }
    __syncthreads();
    if (tid == 0) {
        float L = 0.f, C = 0.f, Msum = 0.f;
        for (int j = 0; j < NW; ++j) { L += red[0][j]; C += red[1][j]; Msum += red[2][j]; }
        float comp = (t1v - t0v) * mu_s - al_s * (C - Msum);
        out[b] = L - comp;
    }
}

extern "C" void kernel_launch(void* const* d_in, const int* in_sizes, int n_in,
                              void* d_out, int out_size, void* d_ws, size_t ws_size,
                              hipStream_t stream) {
    (void)n_in; (void)d_ws; (void)ws_size; (void)out_size;
    const float* T     = (const float*)d_in[0];
    const float* M     = (const float*)d_in[1];
    const float* t0    = (const float*)d_in[2];
    const float* t1    = (const float*)d_in[3];
    const float* mu    = (const float*)d_in[4];
    const float* alpha = (const float*)d_in[5];
    const float* beta  = (const float*)d_in[6];
    float* out = (float*)d_out;

    const int B = in_sizes[2];            // t0 has B elements
    const int N = in_sizes[0] / B;        // 4096

    hawkes_kernel<<<B, NB, 0, stream>>>(T, M, t0, t1, mu, alpha, beta, out, N);
}